// Round 9
// baseline (620.653 us; speedup 1.0000x reference)
//
#include <hip/hip_runtime.h>
#include <hip/hip_bf16.h>

#define V     49152
#define NNZ   442368
#define EPS   1e-5f
#define VOUT  12288

typedef __attribute__((ext_vector_type(8))) short bf16x8;
typedef __attribute__((ext_vector_type(4))) float f32x4;

__device__ __forceinline__ unsigned short f2b(float f) {
    __hip_bfloat16 h = __float2bfloat16(f);
    return *reinterpret_cast<unsigned short*>(&h);
}
__device__ __forceinline__ float b2f(unsigned short u) {
    return __uint_as_float((unsigned)u << 16);
}

// ---------------- row_ptr via binary search + zero stats ----------------
__global__ __launch_bounds__(256) void k_rowptr(const int* __restrict__ rows,
                                                int* __restrict__ rp,
                                                float* __restrict__ stats) {
    int r = blockIdx.x * blockDim.x + threadIdx.x;
    if (r <= V) {
        int lo = 0, hi = NNZ;
        while (lo < hi) {
            int m = (lo + hi) >> 1;
            if (rows[m] < r) lo = m + 1; else hi = m;
        }
        rp[r] = lo;
    }
    if (blockIdx.x == 0 && threadIdx.x < 256) stats[threadIdx.x] = 0.f;
}

// ---------------- transpose x [B,V,32] f32 -> xbf [V, b*32+i] bf16 ----------------
__global__ __launch_bounds__(256) void k_xpose(const float* __restrict__ x,
                                               unsigned short* __restrict__ xbf) {
    int id = blockIdx.x * 256 + threadIdx.x;   // V*128 ids
    int i4 = id & 7;
    int b  = (id >> 3) & 15;
    int v  = id >> 7;
    float4 q = *(const float4*)&x[((size_t)b * V + v) * 32 + i4 * 4];
    ushort4 u = {f2b(q.x), f2b(q.y), f2b(q.z), f2b(q.w)};
    *(ushort4*)&xbf[(size_t)v * 512 + b * 32 + i4 * 4] = u;
}

// ---------------- W [4][32][64] f32 -> fragment-ordered bf16 Wfrag[(ks,ct,lane,j)] ----------------
__global__ __launch_bounds__(256) void k_wconv(const float* __restrict__ W,
                                               unsigned short* __restrict__ Wfrag) {
    int d = blockIdx.x * 256 + threadIdx.x;    // 8192 total
    int j = d & 7, lane = (d >> 3) & 63, ct = (d >> 9) & 3, ks = d >> 11;
    int k128 = ks * 32 + (lane >> 4) * 8 + j;
    int o = ct * 16 + (lane & 15);
    Wfrag[d] = f2b(W[k128 * 64 + o]);
}

// ---------------- X1 = L @ X0 : one wave per vertex, bf16 gather ----------------
__global__ __launch_bounds__(256) void k_spmm1(const unsigned short* __restrict__ xbf,
                                               const int* __restrict__ cols,
                                               const float* __restrict__ vals,
                                               const int* __restrict__ rp,
                                               unsigned short* __restrict__ X1) {
    int t = threadIdx.x;
    int wave = t >> 6, lane = t & 63;
    int v = blockIdx.x * 4 + wave;
    int f0 = lane * 8;
    int s = rp[v], e = rp[v + 1];
    float a[8] = {0.f, 0.f, 0.f, 0.f, 0.f, 0.f, 0.f, 0.f};
    for (int n = s; n < e; ++n) {
        int c = cols[n];
        float w = vals[n];
        union { unsigned short u[8]; uint4 q; } ld;
        ld.q = *(const uint4*)&xbf[(size_t)c * 512 + f0];
#pragma unroll
        for (int j = 0; j < 8; ++j) a[j] = fmaf(w, b2f(ld.u[j]), a[j]);
    }
    union { unsigned short u[8]; uint4 q; } st;
#pragma unroll
    for (int j = 0; j < 8; ++j) st.u[j] = f2b(a[j]);
    *(uint4*)&X1[(size_t)v * 512 + f0] = st.q;
}

// ---------------- X2 = 2 L @ X1 - X0 ----------------
__global__ __launch_bounds__(256) void k_spmm2(const unsigned short* __restrict__ xbf,
                                               const int* __restrict__ cols,
                                               const float* __restrict__ vals,
                                               const int* __restrict__ rp,
                                               const unsigned short* __restrict__ X1,
                                               unsigned short* __restrict__ X2) {
    int t = threadIdx.x;
    int wave = t >> 6, lane = t & 63;
    int v = blockIdx.x * 4 + wave;
    int f0 = lane * 8;
    int s = rp[v], e = rp[v + 1];
    float a[8] = {0.f, 0.f, 0.f, 0.f, 0.f, 0.f, 0.f, 0.f};
    for (int n = s; n < e; ++n) {
        int c = cols[n];
        float w = vals[n];
        union { unsigned short u[8]; uint4 q; } ld;
        ld.q = *(const uint4*)&X1[(size_t)c * 512 + f0];
#pragma unroll
        for (int j = 0; j < 8; ++j) a[j] = fmaf(w, b2f(ld.u[j]), a[j]);
    }
    union { unsigned short u[8]; uint4 q; } x0;
    x0.q = *(const uint4*)&xbf[(size_t)v * 512 + f0];
    union { unsigned short u[8]; uint4 q; } st;
#pragma unroll
    for (int j = 0; j < 8; ++j) st.u[j] = f2b(2.f * a[j] - b2f(x0.u[j]));
    *(uint4*)&X2[(size_t)v * 512 + f0] = st.q;
}

// ---------------- X3 = 2 L @ X2 - X1 ----------------
__global__ __launch_bounds__(256) void k_spmm3(const unsigned short* __restrict__ X1,
                                               const int* __restrict__ cols,
                                               const float* __restrict__ vals,
                                               const int* __restrict__ rp,
                                               const unsigned short* __restrict__ X2,
                                               unsigned short* __restrict__ X3) {
    int t = threadIdx.x;
    int wave = t >> 6, lane = t & 63;
    int v = blockIdx.x * 4 + wave;
    int f0 = lane * 8;
    int s = rp[v], e = rp[v + 1];
    float a[8] = {0.f, 0.f, 0.f, 0.f, 0.f, 0.f, 0.f, 0.f};
    for (int n = s; n < e; ++n) {
        int c = cols[n];
        float w = vals[n];
        union { unsigned short u[8]; uint4 q; } ld;
        ld.q = *(const uint4*)&X2[(size_t)c * 512 + f0];
#pragma unroll
        for (int j = 0; j < 8; ++j) a[j] = fmaf(w, b2f(ld.u[j]), a[j]);
    }
    union { unsigned short u[8]; uint4 q; } p1;
    p1.q = *(const uint4*)&X1[(size_t)v * 512 + f0];
    union { unsigned short u[8]; uint4 q; } st;
#pragma unroll
    for (int j = 0; j < 8; ++j) st.u[j] = f2b(2.f * a[j] - b2f(p1.u[j]));
    *(uint4*)&X3[(size_t)v * 512 + f0] = st.q;
}

// ---------------- MFMA einsum: Y[v][b][o] = sum_ks A_ks[v] @ W_ks  + BN stats ----------------
// One wave per vertex (16 rows), 4 col-tiles of 16; K = 4 steps of 32.
__global__ __launch_bounds__(256) void k_einsum(const unsigned short* __restrict__ xbf,
                                                const unsigned short* __restrict__ X1,
                                                const unsigned short* __restrict__ X2,
                                                const unsigned short* __restrict__ X3,
                                                const unsigned short* __restrict__ Wfrag,
                                                unsigned short* __restrict__ Y,
                                                float* __restrict__ stats) {
    __shared__ unsigned short sB[8192];   // 16 KB, fragment-ordered W
    __shared__ unsigned short sY[4096];   // 8 KB bounce for coalesced Y write
    __shared__ float lsum[64], lsq[64];

    int t = threadIdx.x;
    int wave = t >> 6, lane = t & 63;
    int v = blockIdx.x * 4 + wave;

    // stage Wfrag -> LDS (4 x uint4 per thread, coalesced)
#pragma unroll
    for (int m = 0; m < 4; ++m) {
        int d = t + m * 256;
        *(uint4*)&sB[d * 8] = *(const uint4*)&Wfrag[d * 8];
    }
    if (t < 64) { lsum[t] = 0.f; lsq[t] = 0.f; }
    __syncthreads();

    f32x4 acc[4];
#pragma unroll
    for (int ct = 0; ct < 4; ++ct) acc[ct] = (f32x4){0.f, 0.f, 0.f, 0.f};

    const unsigned short* srcs[4] = {xbf, X1, X2, X3};
    size_t abase = (size_t)v * 512 + (lane & 15) * 32 + (lane >> 4) * 8;
#pragma unroll
    for (int ks = 0; ks < 4; ++ks) {
        bf16x8 a = *(const bf16x8*)&srcs[ks][abase];
#pragma unroll
        for (int ct = 0; ct < 4; ++ct) {
            bf16x8 b = *(const bf16x8*)&sB[((ks * 4 + ct) * 64 + lane) * 8];
            acc[ct] = __builtin_amdgcn_mfma_f32_16x16x32_bf16(a, b, acc[ct], 0, 0, 0);
        }
    }

    // BN partial sums: acc[ct][g] -> channel o = ct*16 + (lane&15), rows g
#pragma unroll
    for (int ct = 0; ct < 4; ++ct) {
        float s = acc[ct].x + acc[ct].y + acc[ct].z + acc[ct].w;
        float q = acc[ct].x * acc[ct].x + acc[ct].y * acc[ct].y
                + acc[ct].z * acc[ct].z + acc[ct].w * acc[ct].w;
        atomicAdd(&lsum[ct * 16 + (lane & 15)], s);
        atomicAdd(&lsq[ct * 16 + (lane & 15)], q);
    }

    // bounce C into LDS: sY[wave][b][o], b = (lane>>4)*4+g, o = ct*16+(lane&15)
#pragma unroll
    for (int ct = 0; ct < 4; ++ct) {
        int o = ct * 16 + (lane & 15);
        int bb = (lane >> 4) * 4;
        sY[wave * 1024 + (bb + 0) * 64 + o] = f2b(acc[ct].x);
        sY[wave * 1024 + (bb + 1) * 64 + o] = f2b(acc[ct].y);
        sY[wave * 1024 + (bb + 2) * 64 + o] = f2b(acc[ct].z);
        sY[wave * 1024 + (bb + 3) * 64 + o] = f2b(acc[ct].w);
    }
    __syncthreads();

    // coalesced Y write: block covers 4 vertex-rows x 1024 bf16 = 8 KB
    size_t ybase = (size_t)blockIdx.x * 4096 + t * 16;
    *(uint4*)&Y[ybase]     = *(const uint4*)&sY[t * 16];
    *(uint4*)&Y[ybase + 8] = *(const uint4*)&sY[t * 16 + 8];

    if (t < 64) {
        atomicAdd(&stats[t], lsum[t]);
        atomicAdd(&stats[64 + t], lsq[t]);
    }
}

// ---------------- finalize BN scale/shift ----------------
__global__ void k_bnfin(const float* __restrict__ gamma, const float* __restrict__ beta,
                        float* __restrict__ stats) {
    int o = threadIdx.x;
    if (o < 64) {
        float n = (float)(16 * V);
        float mean = stats[o] / n;
        float var = stats[64 + o] / n - mean * mean;
        float sc = gamma[o] * rsqrtf(var + EPS);
        stats[128 + o] = sc;
        stats[192 + o] = beta[o] - mean * sc;
    }
}

// ---------------- BN apply + ReLU + pool(4), bf16 y in ----------------
__global__ __launch_bounds__(256) void k_pool(const unsigned short* __restrict__ Y,
                                              const float* __restrict__ stats,
                                              float* __restrict__ out) {
    int id = blockIdx.x * blockDim.x + threadIdx.x;
    int o4 = id & 15;
    int b  = (id >> 4) & 15;
    int vp = id >> 8;
    float4 sc = *(const float4*)&stats[128 + o4 * 4];
    float4 sh = *(const float4*)&stats[192 + o4 * 4];
    float ax = 0.f, ay = 0.f, az = 0.f, aw = 0.f;
#pragma unroll
    for (int j = 0; j < 4; ++j) {
        ushort4 u = *(const ushort4*)&Y[(size_t)((vp * 4 + j) * 16 + b) * 64 + o4 * 4];
        float tx = b2f(u.x), ty = b2f(u.y), tz = b2f(u.z), tw = b2f(u.w);
        ax += fmaxf(fmaf(tx, sc.x, sh.x), 0.f);
        ay += fmaxf(fmaf(ty, sc.y, sh.y), 0.f);
        az += fmaxf(fmaf(tz, sc.z, sh.z), 0.f);
        aw += fmaxf(fmaf(tw, sc.w, sh.w), 0.f);
    }
    float4 res = {ax * 0.25f, ay * 0.25f, az * 0.25f, aw * 0.25f};
    *(float4*)&out[(size_t)((b * VOUT + vp) * 16 + o4) * 4] = res;
}

extern "C" void kernel_launch(void* const* d_in, const int* in_sizes, int n_in,
                              void* d_out, int out_size, void* d_ws, size_t ws_size,
                              hipStream_t stream) {
    const float* x     = (const float*)d_in[0];
    const float* vals  = (const float*)d_in[1];
    const float* W     = (const float*)d_in[2];
    const float* gamma = (const float*)d_in[3];
    const float* beta  = (const float*)d_in[4];
    const int*   rows  = (const int*)d_in[5];
    const int*   cols  = (const int*)d_in[6];
    float* out = (float*)d_out;

    char* ws = (char*)d_ws;
    unsigned short* xbf = (unsigned short*)ws;                   //  50,331,648 B
    unsigned short* X1  = (unsigned short*)(ws + 50331648UL);    //  50,331,648 B
    unsigned short* X2  = (unsigned short*)(ws + 100663296UL);   //  50,331,648 B
    unsigned short* X3  = (unsigned short*)(ws + 150994944UL);   //  50,331,648 B
    unsigned short* Y   = (unsigned short*)(ws + 201326592UL);   // 100,663,296 B (bf16 [v][b][o])
    int*   rp    = (int*)(ws + 301989888UL);                     // 196,612 B (ends 302186500)
    float* stats = (float*)(ws + 302190592UL);                   // 1 KB (past rp, padded)
    unsigned short* Wfrag = (unsigned short*)(ws + 302194688UL); // 16 KB

    k_rowptr<<<193, 256, 0, stream>>>(rows, rp, stats);
    k_xpose<<<V * 128 / 256, 256, 0, stream>>>(x, xbf);
    k_wconv<<<32, 256, 0, stream>>>(W, Wfrag);
    k_spmm1<<<V / 4, 256, 0, stream>>>(xbf, cols, vals, rp, X1);
    k_spmm2<<<V / 4, 256, 0, stream>>>(xbf, cols, vals, rp, X1, X2);
    k_spmm3<<<V / 4, 256, 0, stream>>>(X1, cols, vals, rp, X2, X3);
    k_einsum<<<V / 4, 256, 0, stream>>>(xbf, X1, X2, X3, Wfrag, Y, stats);
    k_bnfin<<<1, 64, 0, stream>>>(gamma, beta, stats);
    k_pool<<<12288, 256, 0, stream>>>(Y, stats, out);
}

// Round 10
// 403.223 us; speedup vs baseline: 1.5392x; 1.5392x over previous
//
#include <hip/hip_runtime.h>
#include <hip/hip_bf16.h>

#define V     49152
#define NNZ   442368
#define EPS   1e-5f
#define VOUT  12288

typedef __attribute__((ext_vector_type(8))) short bf16x8;
typedef __attribute__((ext_vector_type(4))) float f32x4;

__device__ __forceinline__ unsigned short f2b(float f) {
    __hip_bfloat16 h = __float2bfloat16(f);
    return *reinterpret_cast<unsigned short*>(&h);
}
__device__ __forceinline__ float b2f(unsigned short u) {
    return __uint_as_float((unsigned)u << 16);
}

// ---------------- row_ptr via binary search ----------------
__global__ __launch_bounds__(256) void k_rowptr(const int* __restrict__ rows,
                                                int* __restrict__ rp) {
    int r = blockIdx.x * blockDim.x + threadIdx.x;
    if (r <= V) {
        int lo = 0, hi = NNZ;
        while (lo < hi) {
            int m = (lo + hi) >> 1;
            if (rows[m] < r) lo = m + 1; else hi = m;
        }
        rp[r] = lo;
    }
}

// ---------------- transpose x [B,V,32] f32 -> xbf [V, b*32+i] bf16 ----------------
__global__ __launch_bounds__(256) void k_xpose(const float* __restrict__ x,
                                               unsigned short* __restrict__ xbf) {
    int id = blockIdx.x * 256 + threadIdx.x;   // V*128 ids
    int i4 = id & 7;
    int b  = (id >> 3) & 15;
    int v  = id >> 7;
    float4 q = *(const float4*)&x[((size_t)b * V + v) * 32 + i4 * 4];
    ushort4 u = {f2b(q.x), f2b(q.y), f2b(q.z), f2b(q.w)};
    *(ushort4*)&xbf[(size_t)v * 512 + b * 32 + i4 * 4] = u;
}

// ---------------- W [4][32][64] f32 -> fragment-ordered bf16 Wfrag[(ks,ct,lane,j)] ----------------
__global__ __launch_bounds__(256) void k_wconv(const float* __restrict__ W,
                                               unsigned short* __restrict__ Wfrag) {
    int d = blockIdx.x * 256 + threadIdx.x;    // 8192 total
    int j = d & 7, lane = (d >> 3) & 63, ct = (d >> 9) & 3, ks = d >> 11;
    int k128 = ks * 32 + (lane >> 4) * 8 + j;
    int o = ct * 16 + (lane & 15);
    Wfrag[d] = f2b(W[k128 * 64 + o]);
}

// ---------------- X1 = L @ X0 : one wave per vertex, bf16 gather ----------------
__global__ __launch_bounds__(256) void k_spmm1(const unsigned short* __restrict__ xbf,
                                               const int* __restrict__ cols,
                                               const float* __restrict__ vals,
                                               const int* __restrict__ rp,
                                               unsigned short* __restrict__ X1) {
    int t = threadIdx.x;
    int wave = t >> 6, lane = t & 63;
    int v = blockIdx.x * 4 + wave;
    int f0 = lane * 8;
    int s = rp[v], e = rp[v + 1];
    float a[8] = {0.f, 0.f, 0.f, 0.f, 0.f, 0.f, 0.f, 0.f};
    for (int n = s; n < e; ++n) {
        int c = cols[n];
        float w = vals[n];
        union { unsigned short u[8]; uint4 q; } ld;
        ld.q = *(const uint4*)&xbf[(size_t)c * 512 + f0];
#pragma unroll
        for (int j = 0; j < 8; ++j) a[j] = fmaf(w, b2f(ld.u[j]), a[j]);
    }
    union { unsigned short u[8]; uint4 q; } st;
#pragma unroll
    for (int j = 0; j < 8; ++j) st.u[j] = f2b(a[j]);
    *(uint4*)&X1[(size_t)v * 512 + f0] = st.q;
}

// ---------------- X2 = 2 L @ X1 - X0 ----------------
__global__ __launch_bounds__(256) void k_spmm2(const unsigned short* __restrict__ xbf,
                                               const int* __restrict__ cols,
                                               const float* __restrict__ vals,
                                               const int* __restrict__ rp,
                                               const unsigned short* __restrict__ X1,
                                               unsigned short* __restrict__ X2) {
    int t = threadIdx.x;
    int wave = t >> 6, lane = t & 63;
    int v = blockIdx.x * 4 + wave;
    int f0 = lane * 8;
    int s = rp[v], e = rp[v + 1];
    float a[8] = {0.f, 0.f, 0.f, 0.f, 0.f, 0.f, 0.f, 0.f};
    for (int n = s; n < e; ++n) {
        int c = cols[n];
        float w = vals[n];
        union { unsigned short u[8]; uint4 q; } ld;
        ld.q = *(const uint4*)&X1[(size_t)c * 512 + f0];
#pragma unroll
        for (int j = 0; j < 8; ++j) a[j] = fmaf(w, b2f(ld.u[j]), a[j]);
    }
    union { unsigned short u[8]; uint4 q; } x0;
    x0.q = *(const uint4*)&xbf[(size_t)v * 512 + f0];
    union { unsigned short u[8]; uint4 q; } st;
#pragma unroll
    for (int j = 0; j < 8; ++j) st.u[j] = f2b(2.f * a[j] - b2f(x0.u[j]));
    *(uint4*)&X2[(size_t)v * 512 + f0] = st.q;
}

// ---------------- X3 = 2 L @ X2 - X1 ----------------
__global__ __launch_bounds__(256) void k_spmm3(const unsigned short* __restrict__ X1,
                                               const int* __restrict__ cols,
                                               const float* __restrict__ vals,
                                               const int* __restrict__ rp,
                                               const unsigned short* __restrict__ X2,
                                               unsigned short* __restrict__ X3) {
    int t = threadIdx.x;
    int wave = t >> 6, lane = t & 63;
    int v = blockIdx.x * 4 + wave;
    int f0 = lane * 8;
    int s = rp[v], e = rp[v + 1];
    float a[8] = {0.f, 0.f, 0.f, 0.f, 0.f, 0.f, 0.f, 0.f};
    for (int n = s; n < e; ++n) {
        int c = cols[n];
        float w = vals[n];
        union { unsigned short u[8]; uint4 q; } ld;
        ld.q = *(const uint4*)&X2[(size_t)c * 512 + f0];
#pragma unroll
        for (int j = 0; j < 8; ++j) a[j] = fmaf(w, b2f(ld.u[j]), a[j]);
    }
    union { unsigned short u[8]; uint4 q; } p1;
    p1.q = *(const uint4*)&X1[(size_t)v * 512 + f0];
    union { unsigned short u[8]; uint4 q; } st;
#pragma unroll
    for (int j = 0; j < 8; ++j) st.u[j] = f2b(2.f * a[j] - b2f(p1.u[j]));
    *(uint4*)&X3[(size_t)v * 512 + f0] = st.q;
}

// ---------------- MFMA einsum (pure): Y[v][b][o] = sum_ks A_ks[v] @ W_ks ----------------
// One wave per vertex (16 rows), 4 col-tiles of 16; K = 4 steps of 32.
__global__ __launch_bounds__(256) void k_einsum(const unsigned short* __restrict__ xbf,
                                                const unsigned short* __restrict__ X1,
                                                const unsigned short* __restrict__ X2,
                                                const unsigned short* __restrict__ X3,
                                                const unsigned short* __restrict__ Wfrag,
                                                unsigned short* __restrict__ Y) {
    __shared__ unsigned short sB[8192];   // 16 KB, fragment-ordered W
    __shared__ unsigned short sY[4096];   // 8 KB bounce for coalesced Y write

    int t = threadIdx.x;
    int wave = t >> 6, lane = t & 63;
    int v = blockIdx.x * 4 + wave;

    // stage Wfrag -> LDS (4 x uint4 per thread, coalesced)
#pragma unroll
    for (int m = 0; m < 4; ++m) {
        int d = t + m * 256;
        *(uint4*)&sB[d * 8] = *(const uint4*)&Wfrag[d * 8];
    }
    __syncthreads();

    f32x4 acc[4];
#pragma unroll
    for (int ct = 0; ct < 4; ++ct) acc[ct] = (f32x4){0.f, 0.f, 0.f, 0.f};

    const unsigned short* srcs[4] = {xbf, X1, X2, X3};
    size_t abase = (size_t)v * 512 + (lane & 15) * 32 + (lane >> 4) * 8;
#pragma unroll
    for (int ks = 0; ks < 4; ++ks) {
        bf16x8 a = *(const bf16x8*)&srcs[ks][abase];
#pragma unroll
        for (int ct = 0; ct < 4; ++ct) {
            bf16x8 b = *(const bf16x8*)&sB[((ks * 4 + ct) * 64 + lane) * 8];
            acc[ct] = __builtin_amdgcn_mfma_f32_16x16x32_bf16(a, b, acc[ct], 0, 0, 0);
        }
    }

    // bounce C into LDS: sY[wave][b][o], b = (lane>>4)*4+g, o = ct*16+(lane&15)
#pragma unroll
    for (int ct = 0; ct < 4; ++ct) {
        int o = ct * 16 + (lane & 15);
        int bb = (lane >> 4) * 4;
        sY[wave * 1024 + (bb + 0) * 64 + o] = f2b(acc[ct].x);
        sY[wave * 1024 + (bb + 1) * 64 + o] = f2b(acc[ct].y);
        sY[wave * 1024 + (bb + 2) * 64 + o] = f2b(acc[ct].z);
        sY[wave * 1024 + (bb + 3) * 64 + o] = f2b(acc[ct].w);
    }
    __syncthreads();

    // coalesced Y write: block covers 4 vertex-rows x 1024 bf16 = 8 KB
    size_t ybase = (size_t)blockIdx.x * 4096 + t * 16;
    *(uint4*)&Y[ybase]     = *(const uint4*)&sY[t * 16];
    *(uint4*)&Y[ybase + 8] = *(const uint4*)&sY[t * 16 + 8];
}

// ---------------- BN stats stage 1: per-block partial sums from Y ----------------
// 256 blocks; block reduces 24576 uint4 (3072 vertex-rows) into partials[bid][128].
__global__ __launch_bounds__(256) void k_bnred1(const unsigned short* __restrict__ Y,
                                                float* __restrict__ partials) {
    __shared__ float lsum[64], lsq[64];
    int t = threadIdx.x;
    if (t < 64) { lsum[t] = 0.f; lsq[t] = 0.f; }
    __syncthreads();
    float s[8] = {0.f, 0.f, 0.f, 0.f, 0.f, 0.f, 0.f, 0.f};
    float q[8] = {0.f, 0.f, 0.f, 0.f, 0.f, 0.f, 0.f, 0.f};
    const uint4* Yq = (const uint4*)Y;
    size_t base = (size_t)blockIdx.x * 24576;
    for (int i = t; i < 24576; i += 256) {   // i&7 constant per thread
        union { unsigned short u[8]; uint4 v; } ld;
        ld.v = Yq[base + i];
#pragma unroll
        for (int j = 0; j < 8; ++j) {
            float f = b2f(ld.u[j]);
            s[j] += f;
            q[j] = fmaf(f, f, q[j]);
        }
    }
    int c0 = (t & 7) * 8;
#pragma unroll
    for (int j = 0; j < 8; ++j) {
        atomicAdd(&lsum[c0 + j], s[j]);
        atomicAdd(&lsq[c0 + j], q[j]);
    }
    __syncthreads();
    if (t < 128)
        partials[blockIdx.x * 128 + t] = (t < 64) ? lsum[t] : lsq[t - 64];
}

// ---------------- BN stats stage 2 + finalize scale/shift ----------------
__global__ void k_bnfin(const float* __restrict__ partials,
                        const float* __restrict__ gamma, const float* __restrict__ beta,
                        float* __restrict__ stats) {
    __shared__ float tot[128];
    int t = threadIdx.x;   // 128 threads
    float s = 0.f;
    for (int i = 0; i < 256; ++i) s += partials[i * 128 + t];
    tot[t] = s;
    __syncthreads();
    if (t < 64) {
        float n = (float)(16 * V);
        float mean = tot[t] / n;
        float var = tot[64 + t] / n - mean * mean;
        float sc = gamma[t] * rsqrtf(var + EPS);
        stats[128 + t] = sc;
        stats[192 + t] = beta[t] - mean * sc;
    }
}

// ---------------- BN apply + ReLU + pool(4), bf16 y in ----------------
__global__ __launch_bounds__(256) void k_pool(const unsigned short* __restrict__ Y,
                                              const float* __restrict__ stats,
                                              float* __restrict__ out) {
    int id = blockIdx.x * blockDim.x + threadIdx.x;
    int o4 = id & 15;
    int b  = (id >> 4) & 15;
    int vp = id >> 8;
    float4 sc = *(const float4*)&stats[128 + o4 * 4];
    float4 sh = *(const float4*)&stats[192 + o4 * 4];
    float ax = 0.f, ay = 0.f, az = 0.f, aw = 0.f;
#pragma unroll
    for (int j = 0; j < 4; ++j) {
        ushort4 u = *(const ushort4*)&Y[(size_t)((vp * 4 + j) * 16 + b) * 64 + o4 * 4];
        float tx = b2f(u.x), ty = b2f(u.y), tz = b2f(u.z), tw = b2f(u.w);
        ax += fmaxf(fmaf(tx, sc.x, sh.x), 0.f);
        ay += fmaxf(fmaf(ty, sc.y, sh.y), 0.f);
        az += fmaxf(fmaf(tz, sc.z, sh.z), 0.f);
        aw += fmaxf(fmaf(tw, sc.w, sh.w), 0.f);
    }
    float4 res = {ax * 0.25f, ay * 0.25f, az * 0.25f, aw * 0.25f};
    *(float4*)&out[(size_t)((b * VOUT + vp) * 16 + o4) * 4] = res;
}

extern "C" void kernel_launch(void* const* d_in, const int* in_sizes, int n_in,
                              void* d_out, int out_size, void* d_ws, size_t ws_size,
                              hipStream_t stream) {
    const float* x     = (const float*)d_in[0];
    const float* vals  = (const float*)d_in[1];
    const float* W     = (const float*)d_in[2];
    const float* gamma = (const float*)d_in[3];
    const float* beta  = (const float*)d_in[4];
    const int*   rows  = (const int*)d_in[5];
    const int*   cols  = (const int*)d_in[6];
    float* out = (float*)d_out;

    char* ws = (char*)d_ws;
    unsigned short* xbf = (unsigned short*)ws;                   //  50,331,648 B
    unsigned short* X1  = (unsigned short*)(ws + 50331648UL);    //  50,331,648 B
    unsigned short* X2  = (unsigned short*)(ws + 100663296UL);   //  50,331,648 B
    unsigned short* X3  = (unsigned short*)(ws + 150994944UL);   //  50,331,648 B
    unsigned short* Y   = (unsigned short*)(ws + 201326592UL);   // 100,663,296 B (bf16 [v][b][o])
    int*   rp    = (int*)(ws + 301989888UL);                     // 196,612 B (ends 302,186,500)
    float* stats = (float*)(ws + 302190592UL);                   // 1 KB
    unsigned short* Wfrag = (unsigned short*)(ws + 302194688UL); // 16 KB (ends 302,211,072)
    float* partials = (float*)(ws + 302211072UL);                // 131,072 B (ends 302,342,144)

    k_rowptr<<<193, 256, 0, stream>>>(rows, rp);
    k_xpose<<<V * 128 / 256, 256, 0, stream>>>(x, xbf);
    k_wconv<<<32, 256, 0, stream>>>(W, Wfrag);
    k_spmm1<<<V / 4, 256, 0, stream>>>(xbf, cols, vals, rp, X1);
    k_spmm2<<<V / 4, 256, 0, stream>>>(xbf, cols, vals, rp, X1, X2);
    k_spmm3<<<V / 4, 256, 0, stream>>>(X1, cols, vals, rp, X2, X3);
    k_einsum<<<V / 4, 256, 0, stream>>>(xbf, X1, X2, X3, Wfrag, Y);
    k_bnred1<<<256, 256, 0, stream>>>(Y, partials);
    k_bnfin<<<1, 128, 0, stream>>>(partials, gamma, beta, stats);
    k_pool<<<12288, 256, 0, stream>>>(Y, stats, out);
}

// Round 11
// 401.283 us; speedup vs baseline: 1.5467x; 1.0048x over previous
//
#include <hip/hip_runtime.h>
#include <hip/hip_bf16.h>

#define V     49152
#define NNZ   442368
#define EPS   1e-5f
#define VOUT  12288

typedef __attribute__((ext_vector_type(8))) short bf16x8;
typedef __attribute__((ext_vector_type(4))) float f32x4;

__device__ __forceinline__ unsigned short f2b(float f) {
    __hip_bfloat16 h = __float2bfloat16(f);
    return *reinterpret_cast<unsigned short*>(&h);
}
__device__ __forceinline__ float b2f(unsigned short u) {
    return __uint_as_float((unsigned)u << 16);
}

// ---------------- row_ptr via binary search ----------------
__global__ __launch_bounds__(256) void k_rowptr(const int* __restrict__ rows,
                                                int* __restrict__ rp) {
    int r = blockIdx.x * blockDim.x + threadIdx.x;
    if (r <= V) {
        int lo = 0, hi = NNZ;
        while (lo < hi) {
            int m = (lo + hi) >> 1;
            if (rows[m] < r) lo = m + 1; else hi = m;
        }
        rp[r] = lo;
    }
}

// ---------------- transpose x [B,V,32] f32 -> xbf [V, b*32+i] bf16 ----------------
__global__ __launch_bounds__(256) void k_xpose(const float* __restrict__ x,
                                               unsigned short* __restrict__ xbf) {
    int id = blockIdx.x * 256 + threadIdx.x;   // V*128 ids
    int i4 = id & 7;
    int b  = (id >> 3) & 15;
    int v  = id >> 7;
    float4 q = *(const float4*)&x[((size_t)b * V + v) * 32 + i4 * 4];
    ushort4 u = {f2b(q.x), f2b(q.y), f2b(q.z), f2b(q.w)};
    *(ushort4*)&xbf[(size_t)v * 512 + b * 32 + i4 * 4] = u;
}

// ---------------- W [4][32][64] f32 -> fragment-ordered bf16 Wfrag[(ks,ct,lane,j)] ----------------
__global__ __launch_bounds__(256) void k_wconv(const float* __restrict__ W,
                                               unsigned short* __restrict__ Wfrag) {
    int d = blockIdx.x * 256 + threadIdx.x;    // 8192 total
    int j = d & 7, lane = (d >> 3) & 63, ct = (d >> 9) & 3, ks = d >> 11;
    int k128 = ks * 32 + (lane >> 4) * 8 + j;
    int o = ct * 16 + (lane & 15);
    Wfrag[d] = f2b(W[k128 * 64 + o]);
}

// ---------------- X1 = L @ X0 : one wave per vertex, 2 gathers in flight ----------------
__global__ __launch_bounds__(256) void k_spmm1(const unsigned short* __restrict__ xbf,
                                               const int* __restrict__ cols,
                                               const float* __restrict__ vals,
                                               const int* __restrict__ rp,
                                               unsigned short* __restrict__ X1) {
    int t = threadIdx.x;
    int wave = t >> 6, lane = t & 63;
    int v = blockIdx.x * 4 + wave;
    int f0 = lane * 8;
    int s = rp[v], e = rp[v + 1];
    float a[8] = {0.f, 0.f, 0.f, 0.f, 0.f, 0.f, 0.f, 0.f};
    int n = s;
    for (; n + 1 < e; n += 2) {
        int c0 = cols[n], c1 = cols[n + 1];
        float w0 = vals[n], w1 = vals[n + 1];
        union { unsigned short u[8]; uint4 q; } l0, l1;
        l0.q = *(const uint4*)&xbf[(size_t)c0 * 512 + f0];
        l1.q = *(const uint4*)&xbf[(size_t)c1 * 512 + f0];
#pragma unroll
        for (int j = 0; j < 8; ++j) a[j] = fmaf(w0, b2f(l0.u[j]), a[j]);
#pragma unroll
        for (int j = 0; j < 8; ++j) a[j] = fmaf(w1, b2f(l1.u[j]), a[j]);
    }
    if (n < e) {
        int c0 = cols[n];
        float w0 = vals[n];
        union { unsigned short u[8]; uint4 q; } l0;
        l0.q = *(const uint4*)&xbf[(size_t)c0 * 512 + f0];
#pragma unroll
        for (int j = 0; j < 8; ++j) a[j] = fmaf(w0, b2f(l0.u[j]), a[j]);
    }
    union { unsigned short u[8]; uint4 q; } st;
#pragma unroll
    for (int j = 0; j < 8; ++j) st.u[j] = f2b(a[j]);
    *(uint4*)&X1[(size_t)v * 512 + f0] = st.q;
}

// ---------------- X2 = 2 L @ X1 - X0 : one wave per vertex, 2 gathers in flight ----------------
__global__ __launch_bounds__(256) void k_spmm2(const unsigned short* __restrict__ xbf,
                                               const int* __restrict__ cols,
                                               const float* __restrict__ vals,
                                               const int* __restrict__ rp,
                                               const unsigned short* __restrict__ X1,
                                               unsigned short* __restrict__ X2) {
    int t = threadIdx.x;
    int wave = t >> 6, lane = t & 63;
    int v = blockIdx.x * 4 + wave;
    int f0 = lane * 8;
    int s = rp[v], e = rp[v + 1];
    float a[8] = {0.f, 0.f, 0.f, 0.f, 0.f, 0.f, 0.f, 0.f};
    int n = s;
    for (; n + 1 < e; n += 2) {
        int c0 = cols[n], c1 = cols[n + 1];
        float w0 = vals[n], w1 = vals[n + 1];
        union { unsigned short u[8]; uint4 q; } l0, l1;
        l0.q = *(const uint4*)&X1[(size_t)c0 * 512 + f0];
        l1.q = *(const uint4*)&X1[(size_t)c1 * 512 + f0];
#pragma unroll
        for (int j = 0; j < 8; ++j) a[j] = fmaf(w0, b2f(l0.u[j]), a[j]);
#pragma unroll
        for (int j = 0; j < 8; ++j) a[j] = fmaf(w1, b2f(l1.u[j]), a[j]);
    }
    if (n < e) {
        int c0 = cols[n];
        float w0 = vals[n];
        union { unsigned short u[8]; uint4 q; } l0;
        l0.q = *(const uint4*)&X1[(size_t)c0 * 512 + f0];
#pragma unroll
        for (int j = 0; j < 8; ++j) a[j] = fmaf(w0, b2f(l0.u[j]), a[j]);
    }
    union { unsigned short u[8]; uint4 q; } x0;
    x0.q = *(const uint4*)&xbf[(size_t)v * 512 + f0];
    union { unsigned short u[8]; uint4 q; } st;
#pragma unroll
    for (int j = 0; j < 8; ++j) st.u[j] = f2b(2.f * a[j] - b2f(x0.u[j]));
    *(uint4*)&X2[(size_t)v * 512 + f0] = st.q;
}

// ---- fused: X3 gather (regs->LDS) + MFMA einsum over k=0..3 + BN block-partials + bf16 Y ----
// One wave per vertex; grid V/4. No global atomics: partials[bid][128] written non-atomically.
__global__ __launch_bounds__(256) void k_cheb3(const unsigned short* __restrict__ xbf,
                                               const unsigned short* __restrict__ X1,
                                               const unsigned short* __restrict__ X2,
                                               const unsigned short* __restrict__ Wfrag,
                                               const int* __restrict__ cols,
                                               const float* __restrict__ vals,
                                               const int* __restrict__ rp,
                                               unsigned short* __restrict__ Y,
                                               float* __restrict__ partials) {
    __shared__ unsigned short sB[8192];   // 16 KB fragment-ordered W
    __shared__ float sMix[2048];          // 8 KB: X3 rows (f32), later reused as bf16 Y bounce
    __shared__ float lsum[64], lsq[64];

    int t = threadIdx.x;
    int wave = t >> 6, lane = t & 63;
    int v = blockIdx.x * 4 + wave;

    // stage Wfrag -> LDS
#pragma unroll
    for (int m = 0; m < 4; ++m) {
        int d = t + m * 256;
        *(uint4*)&sB[d * 8] = *(const uint4*)&Wfrag[d * 8];
    }
    if (t < 64) { lsum[t] = 0.f; lsq[t] = 0.f; }

    // ---- phase A: gather X3 row for v into registers, 2 chains in flight ----
    int f0 = lane * 8;
    int s = rp[v], e = rp[v + 1];
    float a[8] = {0.f, 0.f, 0.f, 0.f, 0.f, 0.f, 0.f, 0.f};
    int n = s;
    for (; n + 1 < e; n += 2) {
        int c0 = cols[n], c1 = cols[n + 1];
        float w0 = vals[n], w1 = vals[n + 1];
        union { unsigned short u[8]; uint4 q; } l0, l1;
        l0.q = *(const uint4*)&X2[(size_t)c0 * 512 + f0];
        l1.q = *(const uint4*)&X2[(size_t)c1 * 512 + f0];
#pragma unroll
        for (int j = 0; j < 8; ++j) a[j] = fmaf(w0, b2f(l0.u[j]), a[j]);
#pragma unroll
        for (int j = 0; j < 8; ++j) a[j] = fmaf(w1, b2f(l1.u[j]), a[j]);
    }
    if (n < e) {
        int c0 = cols[n];
        float w0 = vals[n];
        union { unsigned short u[8]; uint4 q; } l0;
        l0.q = *(const uint4*)&X2[(size_t)c0 * 512 + f0];
#pragma unroll
        for (int j = 0; j < 8; ++j) a[j] = fmaf(w0, b2f(l0.u[j]), a[j]);
    }
    union { unsigned short u[8]; uint4 q; } p1;
    p1.q = *(const uint4*)&X1[(size_t)v * 512 + f0];
    float4 xa, xb;
    xa.x = 2.f * a[0] - b2f(p1.u[0]); xa.y = 2.f * a[1] - b2f(p1.u[1]);
    xa.z = 2.f * a[2] - b2f(p1.u[2]); xa.w = 2.f * a[3] - b2f(p1.u[3]);
    xb.x = 2.f * a[4] - b2f(p1.u[4]); xb.y = 2.f * a[5] - b2f(p1.u[5]);
    xb.z = 2.f * a[6] - b2f(p1.u[6]); xb.w = 2.f * a[7] - b2f(p1.u[7]);
    *(float4*)&sMix[wave * 512 + f0]     = xa;
    *(float4*)&sMix[wave * 512 + f0 + 4] = xb;
    __syncthreads();

    // ---- phase B: MFMA over k = 0,1,2 (global) and k = 3 (LDS) ----
    f32x4 acc[4];
#pragma unroll
    for (int ct = 0; ct < 4; ++ct) acc[ct] = (f32x4){0.f, 0.f, 0.f, 0.f};

    const unsigned short* srcs[3] = {xbf, X1, X2};
    size_t abase = (size_t)v * 512 + (lane & 15) * 32 + (lane >> 4) * 8;
#pragma unroll
    for (int ks = 0; ks < 3; ++ks) {
        bf16x8 afr = *(const bf16x8*)&srcs[ks][abase];
#pragma unroll
        for (int ct = 0; ct < 4; ++ct) {
            bf16x8 b = *(const bf16x8*)&sB[((ks * 4 + ct) * 64 + lane) * 8];
            acc[ct] = __builtin_amdgcn_mfma_f32_16x16x32_bf16(afr, b, acc[ct], 0, 0, 0);
        }
    }
    {
        int ao = wave * 512 + (lane & 15) * 32 + (lane >> 4) * 8;
        float4 fa = *(const float4*)&sMix[ao];
        float4 fb = *(const float4*)&sMix[ao + 4];
        union { unsigned short u[8]; bf16x8 h; } af;
        af.u[0] = f2b(fa.x); af.u[1] = f2b(fa.y); af.u[2] = f2b(fa.z); af.u[3] = f2b(fa.w);
        af.u[4] = f2b(fb.x); af.u[5] = f2b(fb.y); af.u[6] = f2b(fb.z); af.u[7] = f2b(fb.w);
#pragma unroll
        for (int ct = 0; ct < 4; ++ct) {
            bf16x8 b = *(const bf16x8*)&sB[((3 * 4 + ct) * 64 + lane) * 8];
            acc[ct] = __builtin_amdgcn_mfma_f32_16x16x32_bf16(af.h, b, acc[ct], 0, 0, 0);
        }
    }

    // BN partial sums from exact accumulators (LDS atomics only)
#pragma unroll
    for (int ct = 0; ct < 4; ++ct) {
        float ss = acc[ct].x + acc[ct].y + acc[ct].z + acc[ct].w;
        float qq = acc[ct].x * acc[ct].x + acc[ct].y * acc[ct].y
                 + acc[ct].z * acc[ct].z + acc[ct].w * acc[ct].w;
        atomicAdd(&lsum[ct * 16 + (lane & 15)], ss);
        atomicAdd(&lsq[ct * 16 + (lane & 15)], qq);
    }

    // reuse sMix as bf16 Y bounce (all X3 reads done)
    __syncthreads();
    unsigned short* sY = (unsigned short*)sMix;
#pragma unroll
    for (int ct = 0; ct < 4; ++ct) {
        int o = ct * 16 + (lane & 15);
        int bb = (lane >> 4) * 4;
        sY[wave * 1024 + (bb + 0) * 64 + o] = f2b(acc[ct].x);
        sY[wave * 1024 + (bb + 1) * 64 + o] = f2b(acc[ct].y);
        sY[wave * 1024 + (bb + 2) * 64 + o] = f2b(acc[ct].z);
        sY[wave * 1024 + (bb + 3) * 64 + o] = f2b(acc[ct].w);
    }
    __syncthreads();

    size_t ybase = (size_t)blockIdx.x * 4096 + t * 16;
    *(uint4*)&Y[ybase]     = *(const uint4*)&sY[t * 16];
    *(uint4*)&Y[ybase + 8] = *(const uint4*)&sY[t * 16 + 8];

    if (t < 128)
        partials[(size_t)blockIdx.x * 128 + t] = (t < 64) ? lsum[t] : lsq[t - 64];
}

// ---------------- reduce partials [12288][128] -> partials2 [48][128] ----------------
__global__ __launch_bounds__(256) void k_bnred2(const float* __restrict__ partials,
                                                float* __restrict__ partials2) {
    __shared__ float ls[128];
    int t = threadIdx.x;
    if (t < 128) ls[t] = 0.f;
    __syncthreads();
    const float4* P = (const float4*)(partials + (size_t)blockIdx.x * 32768);
    float a0 = 0.f, a1 = 0.f, a2 = 0.f, a3 = 0.f;
    for (int i = 0; i < 32; ++i) {
        float4 q = P[i * 256 + t];
        a0 += q.x; a1 += q.y; a2 += q.z; a3 += q.w;
    }
    int c0 = (t * 4) & 127;
    atomicAdd(&ls[c0], a0);
    atomicAdd(&ls[c0 + 1], a1);
    atomicAdd(&ls[c0 + 2], a2);
    atomicAdd(&ls[c0 + 3], a3);
    __syncthreads();
    if (t < 128) partials2[blockIdx.x * 128 + t] = ls[t];
}

// ---------------- finalize BN scale/shift from partials2 ----------------
__global__ void k_bnfin(const float* __restrict__ partials2,
                        const float* __restrict__ gamma, const float* __restrict__ beta,
                        float* __restrict__ stats) {
    __shared__ float tot[128];
    int t = threadIdx.x;   // 128 threads
    float s = 0.f;
    for (int i = 0; i < 48; ++i) s += partials2[i * 128 + t];
    tot[t] = s;
    __syncthreads();
    if (t < 64) {
        float n = (float)(16 * V);
        float mean = tot[t] / n;
        float var = tot[64 + t] / n - mean * mean;
        float sc = gamma[t] * rsqrtf(var + EPS);
        stats[128 + t] = sc;
        stats[192 + t] = beta[t] - mean * sc;
    }
}

// ---------------- BN apply + ReLU + pool(4), bf16 y in ----------------
__global__ __launch_bounds__(256) void k_pool(const unsigned short* __restrict__ Y,
                                              const float* __restrict__ stats,
                                              float* __restrict__ out) {
    int id = blockIdx.x * blockDim.x + threadIdx.x;
    int o4 = id & 15;
    int b  = (id >> 4) & 15;
    int vp = id >> 8;
    float4 sc = *(const float4*)&stats[128 + o4 * 4];
    float4 sh = *(const float4*)&stats[192 + o4 * 4];
    float ax = 0.f, ay = 0.f, az = 0.f, aw = 0.f;
#pragma unroll
    for (int j = 0; j < 4; ++j) {
        ushort4 u = *(const ushort4*)&Y[(size_t)((vp * 4 + j) * 16 + b) * 64 + o4 * 4];
        float tx = b2f(u.x), ty = b2f(u.y), tz = b2f(u.z), tw = b2f(u.w);
        ax += fmaxf(fmaf(tx, sc.x, sh.x), 0.f);
        ay += fmaxf(fmaf(ty, sc.y, sh.y), 0.f);
        az += fmaxf(fmaf(tz, sc.z, sh.z), 0.f);
        aw += fmaxf(fmaf(tw, sc.w, sh.w), 0.f);
    }
    float4 res = {ax * 0.25f, ay * 0.25f, az * 0.25f, aw * 0.25f};
    *(float4*)&out[(size_t)((b * VOUT + vp) * 16 + o4) * 4] = res;
}

extern "C" void kernel_launch(void* const* d_in, const int* in_sizes, int n_in,
                              void* d_out, int out_size, void* d_ws, size_t ws_size,
                              hipStream_t stream) {
    const float* x     = (const float*)d_in[0];
    const float* vals  = (const float*)d_in[1];
    const float* W     = (const float*)d_in[2];
    const float* gamma = (const float*)d_in[3];
    const float* beta  = (const float*)d_in[4];
    const int*   rows  = (const int*)d_in[5];
    const int*   cols  = (const int*)d_in[6];
    float* out = (float*)d_out;

    char* ws = (char*)d_ws;
    unsigned short* xbf = (unsigned short*)ws;                    //  50,331,648 B
    unsigned short* X1  = (unsigned short*)(ws + 50331648UL);     //  50,331,648 B
    unsigned short* X2  = (unsigned short*)(ws + 100663296UL);    //  50,331,648 B
    unsigned short* Y   = (unsigned short*)(ws + 150994944UL);    // 100,663,296 B (ends 251,658,240)
    int*   rp    = (int*)(ws + 251658240UL);                      // 196,612 B (ends 251,854,852)
    float* stats = (float*)(ws + 251858944UL);                    // 1 KB
    unsigned short* Wfrag = (unsigned short*)(ws + 251859968UL);  // 16 KB (ends 251,876,352)
    float* partials  = (float*)(ws + 251877376UL);                // 6,291,456 B (ends 258,168,832)
    float* partials2 = (float*)(ws + 258168832UL);                // 24,576 B

    k_rowptr<<<193, 256, 0, stream>>>(rows, rp);
    k_xpose<<<V * 128 / 256, 256, 0, stream>>>(x, xbf);
    k_wconv<<<32, 256, 0, stream>>>(W, Wfrag);
    k_spmm1<<<V / 4, 256, 0, stream>>>(xbf, cols, vals, rp, X1);
    k_spmm2<<<V / 4, 256, 0, stream>>>(xbf, cols, vals, rp, X1, X2);
    k_cheb3<<<V / 4, 256, 0, stream>>>(xbf, X1, X2, Wfrag, cols, vals, rp, Y, partials);
    k_bnred2<<<48, 256, 0, stream>>>(partials, partials2);
    k_bnfin<<<1, 128, 0, stream>>>(partials2, gamma, beta, stats);
    k_pool<<<12288, 256, 0, stream>>>(Y, stats, out);
}